// Round 13
// baseline (43.902 us; speedup 1.0000x reference)
//
#include <hip/hip_runtime.h>

constexpr int C_ = 1000;
constexpr int A_ = 512;
constexpr int N_ = 65536;
constexpr int CA_ = C_ * A_;
constexpr float ONE_MINUS_M = 0.2f;   // 1 - MOMENTUM

constexpr int TPB   = 512;            // 8 waves
constexpr int NW    = TPB / 64;       // 8 waves per block
constexpr int LPW   = N_ / NW;        // 8192 labels per wave
constexpr int ITERS = LPW / 4 / 64;   // 32 int4-iters per lane

// Native clang vector type: __builtin_nontemporal_load requires a pointer to
// scalar or vector-of-scalar (HIP_vector_type float4 is a struct -> rejected).
typedef float f32x4 __attribute__((ext_vector_type(4)));

// R13 = R9 (best: 29.25us) + NON-TEMPORAL feature loads (via ext_vector_type,
// fixing R12's compile error). Features have zero reuse (each row read once
// device-wide), so bypassing L2 allocation (nt bit on global_load_dwordx4)
// avoids polluting the L2 that the 1000x-reused label array lives in, and
// saves L2 fill bandwidth. Structure unchanged: 1000 blocks x 8 waves (fills
// all 8192 wave slots), wave-autonomous ballot scan, whole-wave coalesced
// 2KB row gather, single final combine barrier.
__global__ __launch_bounds__(TPB, 8) void fused_kernel(
    const float* __restrict__ feat, const int* __restrict__ labels,
    const float* __restrict__ cov, const float* __restrict__ mean,
    const float* __restrict__ amount, float* __restrict__ out)
{
    __shared__ float lds_s[NW][A_];   // 16 KB
    __shared__ float lds_q[NW][A_];   // 16 KB
    __shared__ int   lds_cnt[NW];

    const int c  = blockIdx.x;
    const int wv = threadIdx.x >> 6;
    const int ln = threadIdx.x & 63;

    const int4* lab4  = reinterpret_cast<const int4*>(labels);
    const int   wbase = wv * (LPW / 4);    // int4 index base of this wave
    const int   colb  = ln * 8;            // this lane's 8 columns

    f32x4 s0 = {0,0,0,0}, s1 = {0,0,0,0};
    f32x4 q0 = {0,0,0,0}, q1 = {0,0,0,0};
    int cnt_w = 0;

    int4 L = lab4[wbase + ln];             // prefetched (labels stay cached: reused 1000x)
    for (int it = 0; it < ITERS; ++it) {
        int4 Ln = {0,0,0,0};
        if (it + 1 < ITERS) Ln = lab4[wbase + (it + 1) * 64 + ln];  // in flight

        unsigned long long m[4];
        m[0] = __ballot(L.x == c);
        m[1] = __ballot(L.y == c);
        m[2] = __ballot(L.z == c);
        m[3] = __ballot(L.w == c);
        const int rbase = (wbase + it * 64) * 4;   // row of (bit b, comp k)

        #pragma unroll
        for (int comp = 0; comp < 4; ++comp) {
            unsigned long long mm = m[comp];
            cnt_w += (int)__popcll(mm);
            while (mm) {                            // wave-uniform walk
                const int b = (int)__builtin_ctzll(mm);
                mm &= mm - 1;
                const int row = rbase + 4 * b + comp;
                const float* rp = feat + (size_t)row * A_ + colb;
                // nt loads: zero-reuse stream, bypass L2 allocation
                const f32x4 v0 = __builtin_nontemporal_load(
                    reinterpret_cast<const f32x4*>(rp));
                const f32x4 v1 = __builtin_nontemporal_load(
                    reinterpret_cast<const f32x4*>(rp + 1));
                s0 += v0;
                s1 += v1;
                q0 += v0 * v0;
                q1 += v1 * v1;
            }
        }
        L = Ln;
    }

    // ---- single combine: 8 waves x 512 cols ----
    if (ln == 0) lds_cnt[wv] = cnt_w;      // wave-uniform value
    *reinterpret_cast<f32x4*>(&lds_s[wv][colb])     = s0;
    *reinterpret_cast<f32x4*>(&lds_s[wv][colb + 4]) = s1;
    *reinterpret_cast<f32x4*>(&lds_q[wv][colb])     = q0;
    *reinterpret_cast<f32x4*>(&lds_q[wv][colb + 4]) = q1;
    __syncthreads();

    const int col = threadIdx.x;           // 512 threads -> 512 cols
    float s = 0.f, q = 0.f;
    #pragma unroll
    for (int w = 0; w < NW; ++w) { s += lds_s[w][col]; q += lds_q[w][col]; }
    int cntc = 0;
    #pragma unroll
    for (int w = 0; w < NW; ++w) cntc += lds_cnt[w];

    const float cntf = (float)cntc;
    const float safe = (cntc == 0) ? 1.f : cntf;
    const float inv  = 1.f / safe;
    const float ave  = s * inv;
    const float var  = fmaxf(q * inv - ave * ave, 0.f);

    const float amt   = amount[c];
    const float den   = cntf + amt;
    const float w_raw = (den > 0.f) ? (cntf / den) : 0.f;
    const float w     = (w_raw > 0.f) ? fmaxf(w_raw, ONE_MINUS_M) : 0.f;
    const float omw   = 1.f - w;

    const int idx = c * A_ + col;
    const float m  = mean[idx];
    const float cv = cov[idx];
    const float d  = m - ave;
    out[idx]       = cv * omw + var * w + w * omw * d * d;   // new_cov
    out[CA_ + idx] = m * omw + ave * w;                      // new_mean
    if (col == 0) out[2 * CA_ + c] = amt + cntf;
}

extern "C" void kernel_launch(void* const* d_in, const int* in_sizes, int n_in,
                              void* d_out, int out_size, void* d_ws, size_t ws_size,
                              hipStream_t stream)
{
    const float* feat   = (const float*)d_in[0];
    const int*   labels = (const int*)  d_in[1];
    const float* cov    = (const float*)d_in[2];
    const float* mean   = (const float*)d_in[3];
    const float* amount = (const float*)d_in[4];
    float* out = (float*)d_out;

    fused_kernel<<<C_, TPB, 0, stream>>>(feat, labels, cov, mean, amount, out);
}

// Round 14
// 43.713 us; speedup vs baseline: 1.0043x; 1.0043x over previous
//
#include <hip/hip_runtime.h>

constexpr int C_ = 1000;
constexpr int A_ = 512;
constexpr int N_ = 65536;
constexpr int CA_ = C_ * A_;
constexpr float ONE_MINUS_M = 0.2f;   // 1 - MOMENTUM

constexpr int TPB   = 512;            // 8 waves
constexpr int NW    = TPB / 64;       // 8 waves per block
constexpr int LPW   = N_ / NW;        // 8192 labels per wave
constexpr int ITERS = LPW / 4 / 64;   // 32 int4-iters per lane

// Native clang vector type: __builtin_nontemporal_load requires a pointer to
// scalar or vector-of-scalar (HIP_vector_type float4 is a struct -> rejected).
typedef float f32x4 __attribute__((ext_vector_type(4)));

// R14 = R9 + non-temporal feature loads, with R13's POINTER BUG FIXED:
// rp is float*, so the second 16B load is at rp + 4 (floats), i.e.
// reinterpret_cast<const f32x4*>(rp + 4) — R13's (rp + 1) was a 4-byte
// offset: misaligned, overlapping, cols 5-7 dropped (absmax 1.117, +14us).
// Structure unchanged from R9: 1000 blocks x 8 waves, ballot scan,
// whole-wave coalesced 2KB row gather, single final combine barrier.
__global__ __launch_bounds__(TPB, 8) void fused_kernel(
    const float* __restrict__ feat, const int* __restrict__ labels,
    const float* __restrict__ cov, const float* __restrict__ mean,
    const float* __restrict__ amount, float* __restrict__ out)
{
    __shared__ float lds_s[NW][A_];   // 16 KB
    __shared__ float lds_q[NW][A_];   // 16 KB
    __shared__ int   lds_cnt[NW];

    const int c  = blockIdx.x;
    const int wv = threadIdx.x >> 6;
    const int ln = threadIdx.x & 63;

    const int4* lab4  = reinterpret_cast<const int4*>(labels);
    const int   wbase = wv * (LPW / 4);    // int4 index base of this wave
    const int   colb  = ln * 8;            // this lane's 8 columns

    f32x4 s0 = {0,0,0,0}, s1 = {0,0,0,0};
    f32x4 q0 = {0,0,0,0}, q1 = {0,0,0,0};
    int cnt_w = 0;

    int4 L = lab4[wbase + ln];             // prefetched (labels stay cached: reused 1000x)
    for (int it = 0; it < ITERS; ++it) {
        int4 Ln = {0,0,0,0};
        if (it + 1 < ITERS) Ln = lab4[wbase + (it + 1) * 64 + ln];  // in flight

        unsigned long long m[4];
        m[0] = __ballot(L.x == c);
        m[1] = __ballot(L.y == c);
        m[2] = __ballot(L.z == c);
        m[3] = __ballot(L.w == c);
        const int rbase = (wbase + it * 64) * 4;   // row of (bit b, comp k)

        #pragma unroll
        for (int comp = 0; comp < 4; ++comp) {
            unsigned long long mm = m[comp];
            cnt_w += (int)__popcll(mm);
            while (mm) {                            // wave-uniform walk
                const int b = (int)__builtin_ctzll(mm);
                mm &= mm - 1;
                const int row = rbase + 4 * b + comp;
                const float* rp = feat + (size_t)row * A_ + colb;
                // nt loads: zero-reuse stream, bypass cache allocation.
                // 16-byte offsets in FLOAT units: rp and rp + 4.
                const f32x4 v0 = __builtin_nontemporal_load(
                    reinterpret_cast<const f32x4*>(rp));
                const f32x4 v1 = __builtin_nontemporal_load(
                    reinterpret_cast<const f32x4*>(rp + 4));
                s0 += v0;
                s1 += v1;
                q0 += v0 * v0;
                q1 += v1 * v1;
            }
        }
        L = Ln;
    }

    // ---- single combine: 8 waves x 512 cols ----
    if (ln == 0) lds_cnt[wv] = cnt_w;      // wave-uniform value
    *reinterpret_cast<f32x4*>(&lds_s[wv][colb])     = s0;
    *reinterpret_cast<f32x4*>(&lds_s[wv][colb + 4]) = s1;
    *reinterpret_cast<f32x4*>(&lds_q[wv][colb])     = q0;
    *reinterpret_cast<f32x4*>(&lds_q[wv][colb + 4]) = q1;
    __syncthreads();

    const int col = threadIdx.x;           // 512 threads -> 512 cols
    float s = 0.f, q = 0.f;
    #pragma unroll
    for (int w = 0; w < NW; ++w) { s += lds_s[w][col]; q += lds_q[w][col]; }
    int cntc = 0;
    #pragma unroll
    for (int w = 0; w < NW; ++w) cntc += lds_cnt[w];

    const float cntf = (float)cntc;
    const float safe = (cntc == 0) ? 1.f : cntf;
    const float inv  = 1.f / safe;
    const float ave  = s * inv;
    const float var  = fmaxf(q * inv - ave * ave, 0.f);

    const float amt   = amount[c];
    const float den   = cntf + amt;
    const float w_raw = (den > 0.f) ? (cntf / den) : 0.f;
    const float w     = (w_raw > 0.f) ? fmaxf(w_raw, ONE_MINUS_M) : 0.f;
    const float omw   = 1.f - w;

    const int idx = c * A_ + col;
    const float m  = mean[idx];
    const float cv = cov[idx];
    const float d  = m - ave;
    out[idx]       = cv * omw + var * w + w * omw * d * d;   // new_cov
    out[CA_ + idx] = m * omw + ave * w;                      // new_mean
    if (col == 0) out[2 * CA_ + c] = amt + cntf;
}

extern "C" void kernel_launch(void* const* d_in, const int* in_sizes, int n_in,
                              void* d_out, int out_size, void* d_ws, size_t ws_size,
                              hipStream_t stream)
{
    const float* feat   = (const float*)d_in[0];
    const int*   labels = (const int*)  d_in[1];
    const float* cov    = (const float*)d_in[2];
    const float* mean   = (const float*)d_in[3];
    const float* amount = (const float*)d_in[4];
    float* out = (float*)d_out;

    fused_kernel<<<C_, TPB, 0, stream>>>(feat, labels, cov, mean, amount, out);
}

// Round 15
// 29.366 us; speedup vs baseline: 1.4950x; 1.4886x over previous
//
#include <hip/hip_runtime.h>

constexpr int C_ = 1000;
constexpr int A_ = 512;
constexpr int N_ = 65536;
constexpr int CA_ = C_ * A_;
constexpr float ONE_MINUS_M = 0.2f;   // 1 - MOMENTUM

constexpr int TPB   = 512;            // 8 waves
constexpr int NW    = TPB / 64;       // 8 waves per block
constexpr int LPW   = N_ / NW;        // 8192 labels per wave
constexpr int ITERS = LPW / 4 / 64;   // 32 int4-iters per lane

// R15 = R9 verbatim (best measured: 29.25us). One block per class; each wave
// autonomously scans its 1/8 of the labels (int4 + 64-bit ballot) and gathers
// matching rows itself: lane l owns cols 8l..8l+7, so one row = one coalesced
// 2KB wave read. No LDS lists, no atomics, no mid-kernel barriers — waves
// drift freely, latency hidden by TLP (1000 blocks x 8 waves fills all 8192
// wave slots). Cached (non-nt) loads are essential: L3 serves ~half the
// feature stream (R14's nt variant lost this: 43.7us).
__global__ __launch_bounds__(TPB, 8) void fused_kernel(
    const float* __restrict__ feat, const int* __restrict__ labels,
    const float* __restrict__ cov, const float* __restrict__ mean,
    const float* __restrict__ amount, float* __restrict__ out)
{
    __shared__ float lds_s[NW][A_];   // 16 KB
    __shared__ float lds_q[NW][A_];   // 16 KB
    __shared__ int   lds_cnt[NW];

    const int c  = blockIdx.x;
    const int wv = threadIdx.x >> 6;
    const int ln = threadIdx.x & 63;

    const int4* lab4  = reinterpret_cast<const int4*>(labels);
    const int   wbase = wv * (LPW / 4);    // int4 index base of this wave
    const int   colb  = ln * 8;            // this lane's 8 columns

    float4 s0 = {0,0,0,0}, s1 = {0,0,0,0};
    float4 q0 = {0,0,0,0}, q1 = {0,0,0,0};
    int cnt_w = 0;

    int4 L = lab4[wbase + ln];             // prefetched
    for (int it = 0; it < ITERS; ++it) {
        int4 Ln = {0,0,0,0};
        if (it + 1 < ITERS) Ln = lab4[wbase + (it + 1) * 64 + ln];  // in flight during mask work

        unsigned long long m[4];
        m[0] = __ballot(L.x == c);
        m[1] = __ballot(L.y == c);
        m[2] = __ballot(L.z == c);
        m[3] = __ballot(L.w == c);
        const int rbase = (wbase + it * 64) * 4;   // row of (bit b, comp k) = rbase + 4b + k

        #pragma unroll
        for (int comp = 0; comp < 4; ++comp) {
            unsigned long long mm = m[comp];
            cnt_w += (int)__popcll(mm);
            while (mm) {                            // wave-uniform loop: no divergence
                const int b = (int)__builtin_ctzll(mm);
                mm &= mm - 1;
                const int row = rbase + 4 * b + comp;
                const float* rp = feat + (size_t)row * A_ + colb;
                const float4 v0 = *reinterpret_cast<const float4*>(rp);
                const float4 v1 = *reinterpret_cast<const float4*>(rp + 4);
                s0.x += v0.x; s0.y += v0.y; s0.z += v0.z; s0.w += v0.w;
                s1.x += v1.x; s1.y += v1.y; s1.z += v1.z; s1.w += v1.w;
                q0.x = fmaf(v0.x, v0.x, q0.x); q0.y = fmaf(v0.y, v0.y, q0.y);
                q0.z = fmaf(v0.z, v0.z, q0.z); q0.w = fmaf(v0.w, v0.w, q0.w);
                q1.x = fmaf(v1.x, v1.x, q1.x); q1.y = fmaf(v1.y, v1.y, q1.y);
                q1.z = fmaf(v1.z, v1.z, q1.z); q1.w = fmaf(v1.w, v1.w, q1.w);
            }
        }
        L = Ln;
    }

    // ---- single combine: 8 waves x 512 cols ----
    if (ln == 0) lds_cnt[wv] = cnt_w;      // wave-uniform value
    *reinterpret_cast<float4*>(&lds_s[wv][colb])     = s0;
    *reinterpret_cast<float4*>(&lds_s[wv][colb + 4]) = s1;
    *reinterpret_cast<float4*>(&lds_q[wv][colb])     = q0;
    *reinterpret_cast<float4*>(&lds_q[wv][colb + 4]) = q1;
    __syncthreads();

    const int col = threadIdx.x;           // 512 threads -> 512 cols
    float s = 0.f, q = 0.f;
    #pragma unroll
    for (int w = 0; w < NW; ++w) { s += lds_s[w][col]; q += lds_q[w][col]; }
    int cntc = 0;
    #pragma unroll
    for (int w = 0; w < NW; ++w) cntc += lds_cnt[w];

    const float cntf = (float)cntc;
    const float safe = (cntc == 0) ? 1.f : cntf;
    const float inv  = 1.f / safe;
    const float ave  = s * inv;
    const float var  = fmaxf(q * inv - ave * ave, 0.f);

    const float amt   = amount[c];
    const float den   = cntf + amt;
    const float w_raw = (den > 0.f) ? (cntf / den) : 0.f;
    const float w     = (w_raw > 0.f) ? fmaxf(w_raw, ONE_MINUS_M) : 0.f;
    const float omw   = 1.f - w;

    const int idx = c * A_ + col;
    const float m  = mean[idx];
    const float cv = cov[idx];
    const float d  = m - ave;
    out[idx]       = cv * omw + var * w + w * omw * d * d;   // new_cov
    out[CA_ + idx] = m * omw + ave * w;                      // new_mean
    if (col == 0) out[2 * CA_ + c] = amt + cntf;
}

extern "C" void kernel_launch(void* const* d_in, const int* in_sizes, int n_in,
                              void* d_out, int out_size, void* d_ws, size_t ws_size,
                              hipStream_t stream)
{
    const float* feat   = (const float*)d_in[0];
    const int*   labels = (const int*)  d_in[1];
    const float* cov    = (const float*)d_in[2];
    const float* mean   = (const float*)d_in[3];
    const float* amount = (const float*)d_in[4];
    float* out = (float*)d_out;

    fused_kernel<<<C_, TPB, 0, stream>>>(feat, labels, cov, mean, amount, out);
}